// Round 18
// baseline (1471.407 us; speedup 1.0000x reference)
//
#include <hip/hip_runtime.h>
#include <cstddef>

#define BATCH   8
#define LSEQ    4096
#define DMODEL  128
#define DINNER  256
#define NSTATE  16
#define NLAYER  4
#define MROWS   (BATCH*LSEQ)   // 32768

__device__ __forceinline__ float silu_f(float v) { return v / (1.f + expf(-v)); }
__device__ __forceinline__ float softplus_f(float v) {
  return v > 20.f ? v : log1pf(expf(v));
}

// v_add_f32_dpp row_shr reduction step
template <int CTRL>
__device__ __forceinline__ float dpp_shift(float v) {
  int r = __builtin_amdgcn_update_dpp(0, __float_as_int(v), CTRL, 0xF, 0xF, true);
  return __int_as_float(r);
}

// ---------------------------------------------------------------------------
// in_proj GEMM: [M,128] @ [512,128]^T, 128x128 tile, 8x8 per thread.
// ---------------------------------------------------------------------------
__global__ __launch_bounds__(256) void gemm_in(
    const float* __restrict__ A,       // [M,128]
    const float* __restrict__ W,       // [512,128]
    float* __restrict__ xa,            // [M,256]
    float* __restrict__ zs)            // [M,256]
{
  __shared__ float As[32][132];
  __shared__ float Bs[32][132];
  const int m0 = blockIdx.x * 128;
  const int n0 = blockIdx.y * 128;
  const int t  = threadIdx.x;
  const int tx = t & 15, ty = t >> 4;
  const int sc = (t & 7) * 4, sr = t >> 3;

  float acc[8][8] = {};

  for (int k0 = 0; k0 < 128; k0 += 32) {
#pragma unroll
    for (int p = 0; p < 4; ++p) {
      int r = sr + p * 32;
      float4 a4 = *(const float4*)&A[(size_t)(m0 + r) * 128 + k0 + sc];
      float4 w4 = *(const float4*)&W[(size_t)(n0 + r) * 128 + k0 + sc];
      As[sc + 0][r] = a4.x; As[sc + 1][r] = a4.y;
      As[sc + 2][r] = a4.z; As[sc + 3][r] = a4.w;
      Bs[sc + 0][r] = w4.x; Bs[sc + 1][r] = w4.y;
      Bs[sc + 2][r] = w4.z; Bs[sc + 3][r] = w4.w;
    }
    __syncthreads();
#pragma unroll
    for (int kk = 0; kk < 32; ++kk) {
      float4 a0 = *(const float4*)&As[kk][ty * 4];
      float4 a1 = *(const float4*)&As[kk][ty * 4 + 64];
      float4 b0 = *(const float4*)&Bs[kk][tx * 4];
      float4 b1 = *(const float4*)&Bs[kk][tx * 4 + 64];
      float av[8] = {a0.x, a0.y, a0.z, a0.w, a1.x, a1.y, a1.z, a1.w};
      float bv[8] = {b0.x, b0.y, b0.z, b0.w, b1.x, b1.y, b1.z, b1.w};
#pragma unroll
      for (int i = 0; i < 8; ++i)
#pragma unroll
        for (int j = 0; j < 8; ++j)
          acc[i][j] = fmaf(av[i], bv[j], acc[i][j]);
    }
    __syncthreads();
  }

  const bool zhalf = (n0 >= 256);
#pragma unroll
  for (int ih = 0; ih < 2; ++ih)
#pragma unroll
    for (int i = 0; i < 4; ++i) {
      int m = m0 + ih * 64 + ty * 4 + i;
#pragma unroll
      for (int jh = 0; jh < 2; ++jh) {
        float4 c4 = make_float4(acc[ih*4+i][jh*4+0], acc[ih*4+i][jh*4+1],
                                acc[ih*4+i][jh*4+2], acc[ih*4+i][jh*4+3]);
        int n = n0 + jh * 64 + tx * 4;
        if (!zhalf) {
          *(float4*)&xa[(size_t)m * 256 + n] = c4;
        } else {
          c4.x = silu_f(c4.x); c4.y = silu_f(c4.y);
          c4.z = silu_f(c4.z); c4.w = silu_f(c4.w);
          *(float4*)&zs[(size_t)m * 256 + (n - 256)] = c4;
        }
      }
    }
}

// ---------------------------------------------------------------------------
// out_proj GEMM, fused y*silu(z) + y_t-transpose read. 64x128 tile, 4x8/thr.
// ---------------------------------------------------------------------------
__global__ __launch_bounds__(256) void gemm_yz(
    const float* __restrict__ yT,      // [B,256,L]
    const float* __restrict__ zs,      // [M,256]
    const float* __restrict__ W,       // [128,256]
    float* __restrict__ out0)          // [M,128]
{
  __shared__ float As[32][68];
  __shared__ float Bs[32][132];
  const int m0 = blockIdx.x * 64;
  const int b  = m0 >> 12;
  const int l0 = m0 & (LSEQ - 1);
  const int t  = threadIdx.x;
  const int tx = t & 15, ty = t >> 4;
  const int sc = (t & 7) * 4, sr = t >> 3;
  const int mm = t & 63, kq = t >> 6;

  float acc[4][8] = {};

  for (int k0 = 0; k0 < 256; k0 += 32) {
#pragma unroll
    for (int p = 0; p < 2; ++p) {
      int r = sr + p * 32;
      float4 a4 = *(const float4*)&zs[(size_t)(m0 + r) * 256 + k0 + sc];
      As[sc + 0][r] = a4.x; As[sc + 1][r] = a4.y;
      As[sc + 2][r] = a4.z; As[sc + 3][r] = a4.w;
    }
#pragma unroll
    for (int p = 0; p < 4; ++p) {
      int r = sr + p * 32;
      float4 w4 = *(const float4*)&W[(size_t)r * 256 + k0 + sc];
      Bs[sc + 0][r] = w4.x; Bs[sc + 1][r] = w4.y;
      Bs[sc + 2][r] = w4.z; Bs[sc + 3][r] = w4.w;
    }
    __syncthreads();
#pragma unroll
    for (int p = 0; p < 8; ++p) {
      int k = kq + p * 4;
      As[k][mm] *= yT[((size_t)(b * DINNER + k0 + k)) * LSEQ + l0 + mm];
    }
    __syncthreads();
#pragma unroll
    for (int kk = 0; kk < 32; ++kk) {
      float4 a0 = *(const float4*)&As[kk][ty * 4];
      float4 b0 = *(const float4*)&Bs[kk][tx * 4];
      float4 b1 = *(const float4*)&Bs[kk][tx * 4 + 64];
      float av[4] = {a0.x, a0.y, a0.z, a0.w};
      float bv[8] = {b0.x, b0.y, b0.z, b0.w, b1.x, b1.y, b1.z, b1.w};
#pragma unroll
      for (int i = 0; i < 4; ++i)
#pragma unroll
        for (int j = 0; j < 8; ++j)
          acc[i][j] = fmaf(av[i], bv[j], acc[i][j]);
    }
    __syncthreads();
  }

#pragma unroll
  for (int i = 0; i < 4; ++i) {
    int m = m0 + ty * 4 + i;
#pragma unroll
    for (int jh = 0; jh < 2; ++jh) {
      float4 c4 = make_float4(acc[i][jh*4+0], acc[i][jh*4+1],
                              acc[i][jh*4+2], acc[i][jh*4+3]);
      *(float4*)&out0[(size_t)m * DMODEL + jh * 64 + tx * 4] = c4;
    }
  }
}

// ---------------------------------------------------------------------------
// FUSED conv + x_proj + dt_proj + softplus (unchanged from R15).
// ---------------------------------------------------------------------------
__global__ __launch_bounds__(256) void convproj_dt(
    const float* __restrict__ xa_pre,  // [M,256] pre-conv (gemm_in output)
    const float* __restrict__ cw,      // [256,4]
    const float* __restrict__ cb,      // [256]
    const float* __restrict__ xp_w,    // [40,256]
    const float* __restrict__ dtp_w,   // [256,8]
    const float* __restrict__ dtp_b,   // [256]
    float* __restrict__ xa_t,          // [B,256,L]  (u for scan)
    float* __restrict__ dt_t,          // [B,256,L]
    float* __restrict__ Bt,            // [B,16,L]
    float* __restrict__ Ct)            // [B,16,L]
{
  __shared__ float s_buf[67 * 69];
  __shared__ float s_xpc[40][68];
  __shared__ float s_dtw[256 * 8];
  __shared__ float s_dtb[256];
  __shared__ float s_xa[64][68];
  float (*s_pre)[69]  = (float(*)[69])s_buf;
  float (*s_proj)[44] = (float(*)[44])s_buf;

  const int b  = blockIdx.y;
  const int l0 = blockIdx.x * 64;
  const int t  = threadIdx.x;

  for (int i = t; i < 256 * 8; i += 256) s_dtw[i] = dtp_w[i];
  s_dtb[t] = dtp_b[t];

  const int c_st = t & 63;
  const int r_st = t >> 6;
  const int lA = t & 31;
  const int g  = t >> 5;

  float acc0[5] = {}, acc1[5] = {};

  for (int kc = 0; kc < 256; kc += 64) {
    __syncthreads();
    for (int r = r_st; r < 67; r += 4) {
      int l = l0 - 3 + r;
      float v = 0.f;
      if (l >= 0) v = xa_pre[((size_t)b * LSEQ + l) * 256 + kc + c_st];
      s_pre[r][c_st] = v;
    }
#pragma unroll
    for (int p = 0; p < 10; ++p) {
      int n = r_st + p * 4;
      s_xpc[n][c_st] = xp_w[n * 256 + kc + c_st];
    }
    __syncthreads();
    {
      const int kk = c_st;
      float w0 = cw[(kc + kk) * 4 + 0], w1 = cw[(kc + kk) * 4 + 1];
      float w2 = cw[(kc + kk) * 4 + 2], w3 = cw[(kc + kk) * 4 + 3];
      float cbr = cb[kc + kk];
#pragma unroll
      for (int p = 0; p < 16; ++p) {
        int ll = r_st + p * 4;
        float v = cbr
                + s_pre[ll + 0][kk] * w0
                + s_pre[ll + 1][kk] * w1
                + s_pre[ll + 2][kk] * w2
                + s_pre[ll + 3][kk] * w3;
        s_xa[ll][kk] = silu_f(v);
      }
    }
    __syncthreads();
    {
      const int lw = c_st;
#pragma unroll
      for (int p = 0; p < 16; ++p) {
        int kw = r_st + p * 4;
        xa_t[((size_t)(b * DINNER + kc + kw)) * LSEQ + l0 + lw] = s_xa[lw][kw];
      }
    }
#pragma unroll
    for (int kk = 0; kk < 64; kk += 4) {
      float4 a0 = *(const float4*)&s_xa[lA][kk];
      float4 a1 = *(const float4*)&s_xa[lA + 32][kk];
#pragma unroll
      for (int j = 0; j < 5; ++j) {
        float4 w4 = *(const float4*)&s_xpc[g * 5 + j][kk];
        acc0[j] = fmaf(a0.x, w4.x, fmaf(a0.y, w4.y,
                  fmaf(a0.z, w4.z, fmaf(a0.w, w4.w, acc0[j]))));
        acc1[j] = fmaf(a1.x, w4.x, fmaf(a1.y, w4.y,
                  fmaf(a1.z, w4.z, fmaf(a1.w, w4.w, acc1[j]))));
      }
    }
  }
  __syncthreads();
#pragma unroll
  for (int j = 0; j < 5; ++j) {
    s_proj[lA][g * 5 + j]      = acc0[j];
    s_proj[lA + 32][g * 5 + j] = acc1[j];
  }
  __syncthreads();

  const int ll = t & 63;
  const int dgroup = t >> 6;
  float4 p0 = *(const float4*)&s_proj[ll][0];
  float4 p1 = *(const float4*)&s_proj[ll][4];
  for (int j = 0; j < 64; ++j) {
    int dout = dgroup * 64 + j;
    float4 w0 = *(const float4*)&s_dtw[dout * 8];
    float4 w1 = *(const float4*)&s_dtw[dout * 8 + 4];
    float v = s_dtb[dout]
            + p0.x * w0.x + p0.y * w0.y + p0.z * w0.z + p0.w * w0.w
            + p1.x * w1.x + p1.y * w1.y + p1.z * w1.z + p1.w * w1.w;
    dt_t[((size_t)(b * DINNER + dout)) * LSEQ + l0 + ll] = softplus_f(v);
  }
  if (t < 64) {
#pragma unroll
    for (int nn = 0; nn < 16; ++nn)
      Bt[((size_t)(b * NSTATE + nn)) * LSEQ + l0 + t] = s_proj[t][8 + nn];
  } else if (t < 128) {
    int lw = t - 64;
#pragma unroll
    for (int nn = 0; nn < 16; ++nn)
      Ct[((size_t)(b * NSTATE + nn)) * LSEQ + l0 + lw] = s_proj[lw][24 + nn];
  }
}

// ---------------------------------------------------------------------------
// Selective scan — same per-step arithmetic as R9/R17 (bit-identical), but
// 16-STEP groups (NG=256) instead of 8. Rationale: measured 760 cyc per
// 8-step group fits compute(g) overlapping latency(g+1) at group-granular
// load placement (depth ~1). With 16-step groups, compute(g) ~600 cyc covers
// the ~600 cyc L3 latency of g+1's loads -> exposure ~0, ~44 cyc/step.
// Staging: 2 ring slots x 16 float4 = 128 VGPR (+~50 working) — no spill at
// <=256, occupancy (2 waves/CU) unaffected.
// ---------------------------------------------------------------------------
__global__ __launch_bounds__(64) void scan_k(
    const float* __restrict__ dt_t, const float* __restrict__ u_t,
    const float* __restrict__ Bt,   const float* __restrict__ Ct,
    const float* __restrict__ A_log, const float* __restrict__ Dp,
    float* __restrict__ y_t)
{
  const int blk = blockIdx.x;
  const int b   = blk >> 6;
  const int d0  = (blk & 63) * 4;
  const int lane = threadIdx.x;
  const int g = lane >> 4;
  const int n = lane & 15;
  const int d = d0 + g;

  const float Aa = -expf(A_log[d * NSTATE + n]);
  const float Dv = Dp[d];
  const float4* dtp = (const float4*)(dt_t + ((size_t)(b * DINNER + d)) * LSEQ);
  const float4* up  = (const float4*)(u_t  + ((size_t)(b * DINNER + d)) * LSEQ);
  const float4* Bp  = (const float4*)(Bt + ((size_t)(b * NSTATE + n)) * LSEQ);
  const float4* Cp  = (const float4*)(Ct + ((size_t)(b * NSTATE + n)) * LSEQ);
  float4* yp = (float4*)(y_t + ((size_t)(b * DINNER + d)) * LSEQ);

  const int NG = LSEQ / 16;            // 256 groups of 16 steps
  float4 Rd[2][4], Ru[2][4], Rb[2][4], Rc[2][4];   // 2-slot ring
  float h = 0.f;

#define LOAD_GRP(s, grp) do {                                            \
    int _gg = (grp) < NG ? (grp) : NG - 1;                               \
    int _base = _gg * 4;                                                 \
    _Pragma("unroll")                                                    \
    for (int q = 0; q < 4; ++q) {                                        \
      Rd[s][q] = dtp[_base + q];  Ru[s][q] = up[_base + q];              \
      Rb[s][q] = Bp[_base + q];   Rc[s][q] = Cp[_base + q];              \
    }                                                                    \
  } while (0)

#define COMP_GRP(s, grp) do {                                            \
    float p[16], us16[16];                                               \
    _Pragma("unroll")                                                    \
    for (int q = 0; q < 4; ++q) {                                        \
      float dts[4] = {Rd[s][q].x, Rd[s][q].y, Rd[s][q].z, Rd[s][q].w};   \
      float uq[4]  = {Ru[s][q].x, Ru[s][q].y, Ru[s][q].z, Ru[s][q].w};   \
      float bv[4]  = {Rb[s][q].x, Rb[s][q].y, Rb[s][q].z, Rb[s][q].w};   \
      float cv[4]  = {Rc[s][q].x, Rc[s][q].y, Rc[s][q].z, Rc[s][q].w};   \
      _Pragma("unroll")                                                  \
      for (int st = 0; st < 4; ++st) {                                   \
        int i = q * 4 + st;                                              \
        float a = __expf(dts[st] * Aa);                                  \
        h = fmaf(a, h, (dts[st] * uq[st]) * bv[st]);                     \
        p[i] = h * cv[st];                                               \
        us16[i] = uq[st];                                                \
      }                                                                  \
    }                                                                    \
    _Pragma("unroll")                                                    \
    for (int i = 0; i < 16; ++i) p[i] += dpp_shift<0x118>(p[i]);         \
    _Pragma("unroll")                                                    \
    for (int i = 0; i < 16; ++i) p[i] += dpp_shift<0x114>(p[i]);         \
    _Pragma("unroll")                                                    \
    for (int i = 0; i < 16; ++i) p[i] += dpp_shift<0x112>(p[i]);         \
    _Pragma("unroll")                                                    \
    for (int i = 0; i < 16; ++i) p[i] += dpp_shift<0x111>(p[i]);         \
    if (n == 0) {                                                        \
      _Pragma("unroll")                                                  \
      for (int q = 0; q < 4; ++q)                                        \
        yp[(grp) * 4 + q] = make_float4(                                 \
            fmaf(us16[q*4+0], Dv, p[q*4+0]),                             \
            fmaf(us16[q*4+1], Dv, p[q*4+1]),                             \
            fmaf(us16[q*4+2], Dv, p[q*4+2]),                             \
            fmaf(us16[q*4+3], Dv, p[q*4+3]));                            \
    }                                                                    \
  } while (0)

  LOAD_GRP(0, 0);
  for (int it = 0; it < NG; it += 2) {
    LOAD_GRP(1, it + 1);
    COMP_GRP(0, it);
    LOAD_GRP(0, it + 2);
    COMP_GRP(1, it + 1);
  }
#undef LOAD_GRP
#undef COMP_GRP
}

// ---------------------------------------------------------------------------
extern "C" void kernel_launch(void* const* d_in, const int* in_sizes, int n_in,
                              void* d_out, int out_size, void* d_ws, size_t ws_size,
                              hipStream_t stream) {
  const float* x_in  = (const float*)d_in[0];
  const float* w_in  = (const float*)d_in[1];   // [4,512,128]
  const float* cw    = (const float*)d_in[2];   // [4,256,4]
  const float* cb    = (const float*)d_in[3];   // [4,256]
  const float* xpw   = (const float*)d_in[4];   // [4,40,256]
  const float* dtw   = (const float*)d_in[5];   // [4,256,8]
  const float* dtb   = (const float*)d_in[6];   // [4,256]
  const float* alog  = (const float*)d_in[7];   // [4,256,16]
  const float* Dp    = (const float*)d_in[8];   // [4,256]
  const float* ow    = (const float*)d_in[9];   // [4,128,256]
  float* out = (float*)d_out;

  const size_t M = MROWS;
  float* f0 = (float*)d_ws;            // x ping  [M,128]
  float* f1 = f0 + M * 128;            // x pong  [M,128]
  float* f2 = f1 + M * 128;            // xa_pre [M,256]
  float* f3 = f2 + M * 256;            // zs = silu(z) [M,256]
  float* f4 = f3 + M * 256;            // xa_t = u [B,256,L]
  float* f6 = f4 + M * 256;            // Bt [B,16,L]
  float* f7 = f6 + M * 16;             // Ct [B,16,L]
  float* f8 = f7 + M * 16;             // dt_t -> y_t (in-place) [B,256,L]

  const float* cur = x_in;
  for (int i = 0; i < NLAYER; ++i) {
    float* xout = (i == NLAYER - 1) ? out : ((i % 2 == 0) ? f0 : f1);
    const float* wi  = w_in + (size_t)i * 512 * 128;
    const float* cwi = cw   + (size_t)i * 256 * 4;
    const float* cbi = cb   + (size_t)i * 256;
    const float* xpi = xpw  + (size_t)i * 40 * 256;
    const float* dwi = dtw  + (size_t)i * 256 * 8;
    const float* dbi = dtb  + (size_t)i * 256;
    const float* ali = alog + (size_t)i * 256 * 16;
    const float* dpi = Dp   + (size_t)i * 256;
    const float* owi = ow   + (size_t)i * 128 * 256;

    // 1. in_proj (128x128 tile): -> xa_pre(f2), silu(z)(f3)
    gemm_in<<<dim3(MROWS / 128, 4), 256, 0, stream>>>(cur, wi, f2, f3);
    // 2. fused conv + x_proj + dt_proj -> xa_t(f4), dt_t(f8), Bt(f6), Ct(f7)
    convproj_dt<<<dim3(LSEQ / 64, BATCH), 256, 0, stream>>>(
        f2, cwi, cbi, xpi, dwi, dbi, f4, f8, f6, f7);
    // 3. selective scan (16-step groups) -> y_t in-place over dt_t (f8)
    scan_k<<<dim3(BATCH * DINNER / 4), 64, 0, stream>>>(
        f8, f4, f6, f7, ali, dpi, f8);
    // 4. out_proj (64x128 tile) with fused y*silu(z) + transpose -> xout
    gemm_yz<<<dim3(MROWS / 64, 1), 256, 0, stream>>>(f8, f3, owi, xout);

    cur = xout;
  }
}

// Round 19
// 1361.795 us; speedup vs baseline: 1.0805x; 1.0805x over previous
//
#include <hip/hip_runtime.h>
#include <cstddef>

#define BATCH   8
#define LSEQ    4096
#define DMODEL  128
#define DINNER  256
#define NSTATE  16
#define NLAYER  4
#define MROWS   (BATCH*LSEQ)   // 32768

__device__ __forceinline__ float silu_f(float v) { return v / (1.f + expf(-v)); }
__device__ __forceinline__ float softplus_f(float v) {
  return v > 20.f ? v : log1pf(expf(v));
}

// v_add_f32_dpp row_shr reduction step
template <int CTRL>
__device__ __forceinline__ float dpp_shift(float v) {
  int r = __builtin_amdgcn_update_dpp(0, __float_as_int(v), CTRL, 0xF, 0xF, true);
  return __int_as_float(r);
}

// ---------------------------------------------------------------------------
// in_proj GEMM: [M,128] @ [512,128]^T, 128x128 tile, 8x8 per thread.
// A-tile global loads for chunk k+1 are prefetched into registers during
// chunk k's compute (sink-proof: the values must materialize to be written
// to LDS). W stays direct (VGPR budget: keep <=128 for 4 waves/SIMD).
// fmaf order unchanged -> bit-identical.
// ---------------------------------------------------------------------------
__global__ __launch_bounds__(256) void gemm_in(
    const float* __restrict__ A,       // [M,128]
    const float* __restrict__ W,       // [512,128]
    float* __restrict__ xa,            // [M,256]
    float* __restrict__ zs)            // [M,256]
{
  __shared__ float As[32][132];
  __shared__ float Bs[32][132];
  const int m0 = blockIdx.x * 128;
  const int n0 = blockIdx.y * 128;
  const int t  = threadIdx.x;
  const int tx = t & 15, ty = t >> 4;
  const int sc = (t & 7) * 4, sr = t >> 3;

  float acc[8][8] = {};
  float4 pa[4];

  // prologue: load chunk 0's A rows into registers
#pragma unroll
  for (int p = 0; p < 4; ++p)
    pa[p] = *(const float4*)&A[(size_t)(m0 + sr + p * 32) * 128 + sc];

  for (int k0 = 0; k0 < 128; k0 += 32) {
#pragma unroll
    for (int p = 0; p < 4; ++p) {
      int r = sr + p * 32;
      float4 w4 = *(const float4*)&W[(size_t)(n0 + r) * 128 + k0 + sc];
      As[sc + 0][r] = pa[p].x; As[sc + 1][r] = pa[p].y;
      As[sc + 2][r] = pa[p].z; As[sc + 3][r] = pa[p].w;
      Bs[sc + 0][r] = w4.x; Bs[sc + 1][r] = w4.y;
      Bs[sc + 2][r] = w4.z; Bs[sc + 3][r] = w4.w;
    }
    __syncthreads();
    if (k0 + 32 < 128) {
#pragma unroll
      for (int p = 0; p < 4; ++p)
        pa[p] = *(const float4*)&A[(size_t)(m0 + sr + p * 32) * 128
                                   + (k0 + 32) + sc];
    }
#pragma unroll
    for (int kk = 0; kk < 32; ++kk) {
      float4 a0 = *(const float4*)&As[kk][ty * 4];
      float4 a1 = *(const float4*)&As[kk][ty * 4 + 64];
      float4 b0 = *(const float4*)&Bs[kk][tx * 4];
      float4 b1 = *(const float4*)&Bs[kk][tx * 4 + 64];
      float av[8] = {a0.x, a0.y, a0.z, a0.w, a1.x, a1.y, a1.z, a1.w};
      float bv[8] = {b0.x, b0.y, b0.z, b0.w, b1.x, b1.y, b1.z, b1.w};
#pragma unroll
      for (int i = 0; i < 8; ++i)
#pragma unroll
        for (int j = 0; j < 8; ++j)
          acc[i][j] = fmaf(av[i], bv[j], acc[i][j]);
    }
    __syncthreads();
  }

  const bool zhalf = (n0 >= 256);
#pragma unroll
  for (int ih = 0; ih < 2; ++ih)
#pragma unroll
    for (int i = 0; i < 4; ++i) {
      int m = m0 + ih * 64 + ty * 4 + i;
#pragma unroll
      for (int jh = 0; jh < 2; ++jh) {
        float4 c4 = make_float4(acc[ih*4+i][jh*4+0], acc[ih*4+i][jh*4+1],
                                acc[ih*4+i][jh*4+2], acc[ih*4+i][jh*4+3]);
        int n = n0 + jh * 64 + tx * 4;
        if (!zhalf) {
          *(float4*)&xa[(size_t)m * 256 + n] = c4;
        } else {
          c4.x = silu_f(c4.x); c4.y = silu_f(c4.y);
          c4.z = silu_f(c4.z); c4.w = silu_f(c4.w);
          *(float4*)&zs[(size_t)m * 256 + (n - 256)] = c4;
        }
      }
    }
}

// ---------------------------------------------------------------------------
// out_proj GEMM, fused y*silu(z) + y_t-transpose read. 64x128 tile, 4x8/thr.
// ---------------------------------------------------------------------------
__global__ __launch_bounds__(256) void gemm_yz(
    const float* __restrict__ yT,      // [B,256,L]
    const float* __restrict__ zs,      // [M,256]
    const float* __restrict__ W,       // [128,256]
    float* __restrict__ out0)          // [M,128]
{
  __shared__ float As[32][68];
  __shared__ float Bs[32][132];
  const int m0 = blockIdx.x * 64;
  const int b  = m0 >> 12;
  const int l0 = m0 & (LSEQ - 1);
  const int t  = threadIdx.x;
  const int tx = t & 15, ty = t >> 4;
  const int sc = (t & 7) * 4, sr = t >> 3;
  const int mm = t & 63, kq = t >> 6;

  float acc[4][8] = {};

  for (int k0 = 0; k0 < 256; k0 += 32) {
#pragma unroll
    for (int p = 0; p < 2; ++p) {
      int r = sr + p * 32;
      float4 a4 = *(const float4*)&zs[(size_t)(m0 + r) * 256 + k0 + sc];
      As[sc + 0][r] = a4.x; As[sc + 1][r] = a4.y;
      As[sc + 2][r] = a4.z; As[sc + 3][r] = a4.w;
    }
#pragma unroll
    for (int p = 0; p < 4; ++p) {
      int r = sr + p * 32;
      float4 w4 = *(const float4*)&W[(size_t)r * 256 + k0 + sc];
      Bs[sc + 0][r] = w4.x; Bs[sc + 1][r] = w4.y;
      Bs[sc + 2][r] = w4.z; Bs[sc + 3][r] = w4.w;
    }
    __syncthreads();
#pragma unroll
    for (int p = 0; p < 8; ++p) {
      int k = kq + p * 4;
      As[k][mm] *= yT[((size_t)(b * DINNER + k0 + k)) * LSEQ + l0 + mm];
    }
    __syncthreads();
#pragma unroll
    for (int kk = 0; kk < 32; ++kk) {
      float4 a0 = *(const float4*)&As[kk][ty * 4];
      float4 b0 = *(const float4*)&Bs[kk][tx * 4];
      float4 b1 = *(const float4*)&Bs[kk][tx * 4 + 64];
      float av[4] = {a0.x, a0.y, a0.z, a0.w};
      float bv[8] = {b0.x, b0.y, b0.z, b0.w, b1.x, b1.y, b1.z, b1.w};
#pragma unroll
      for (int i = 0; i < 4; ++i)
#pragma unroll
        for (int j = 0; j < 8; ++j)
          acc[i][j] = fmaf(av[i], bv[j], acc[i][j]);
    }
    __syncthreads();
  }

#pragma unroll
  for (int i = 0; i < 4; ++i) {
    int m = m0 + ty * 4 + i;
#pragma unroll
    for (int jh = 0; jh < 2; ++jh) {
      float4 c4 = make_float4(acc[i][jh*4+0], acc[i][jh*4+1],
                              acc[i][jh*4+2], acc[i][jh*4+3]);
      *(float4*)&out0[(size_t)m * DMODEL + jh * 64 + tx * 4] = c4;
    }
  }
}

// ---------------------------------------------------------------------------
// FUSED conv + x_proj + dt_proj + softplus (unchanged from R15).
// ---------------------------------------------------------------------------
__global__ __launch_bounds__(256) void convproj_dt(
    const float* __restrict__ xa_pre,  // [M,256] pre-conv (gemm_in output)
    const float* __restrict__ cw,      // [256,4]
    const float* __restrict__ cb,      // [256]
    const float* __restrict__ xp_w,    // [40,256]
    const float* __restrict__ dtp_w,   // [256,8]
    const float* __restrict__ dtp_b,   // [256]
    float* __restrict__ xa_t,          // [B,256,L]  (u for scan)
    float* __restrict__ dt_t,          // [B,256,L]
    float* __restrict__ Bt,            // [B,16,L]
    float* __restrict__ Ct)            // [B,16,L]
{
  __shared__ float s_buf[67 * 69];
  __shared__ float s_xpc[40][68];
  __shared__ float s_dtw[256 * 8];
  __shared__ float s_dtb[256];
  __shared__ float s_xa[64][68];
  float (*s_pre)[69]  = (float(*)[69])s_buf;
  float (*s_proj)[44] = (float(*)[44])s_buf;

  const int b  = blockIdx.y;
  const int l0 = blockIdx.x * 64;
  const int t  = threadIdx.x;

  for (int i = t; i < 256 * 8; i += 256) s_dtw[i] = dtp_w[i];
  s_dtb[t] = dtp_b[t];

  const int c_st = t & 63;
  const int r_st = t >> 6;
  const int lA = t & 31;
  const int g  = t >> 5;

  float acc0[5] = {}, acc1[5] = {};

  for (int kc = 0; kc < 256; kc += 64) {
    __syncthreads();
    for (int r = r_st; r < 67; r += 4) {
      int l = l0 - 3 + r;
      float v = 0.f;
      if (l >= 0) v = xa_pre[((size_t)b * LSEQ + l) * 256 + kc + c_st];
      s_pre[r][c_st] = v;
    }
#pragma unroll
    for (int p = 0; p < 10; ++p) {
      int n = r_st + p * 4;
      s_xpc[n][c_st] = xp_w[n * 256 + kc + c_st];
    }
    __syncthreads();
    {
      const int kk = c_st;
      float w0 = cw[(kc + kk) * 4 + 0], w1 = cw[(kc + kk) * 4 + 1];
      float w2 = cw[(kc + kk) * 4 + 2], w3 = cw[(kc + kk) * 4 + 3];
      float cbr = cb[kc + kk];
#pragma unroll
      for (int p = 0; p < 16; ++p) {
        int ll = r_st + p * 4;
        float v = cbr
                + s_pre[ll + 0][kk] * w0
                + s_pre[ll + 1][kk] * w1
                + s_pre[ll + 2][kk] * w2
                + s_pre[ll + 3][kk] * w3;
        s_xa[ll][kk] = silu_f(v);
      }
    }
    __syncthreads();
    {
      const int lw = c_st;
#pragma unroll
      for (int p = 0; p < 16; ++p) {
        int kw = r_st + p * 4;
        xa_t[((size_t)(b * DINNER + kc + kw)) * LSEQ + l0 + lw] = s_xa[lw][kw];
      }
    }
#pragma unroll
    for (int kk = 0; kk < 64; kk += 4) {
      float4 a0 = *(const float4*)&s_xa[lA][kk];
      float4 a1 = *(const float4*)&s_xa[lA + 32][kk];
#pragma unroll
      for (int j = 0; j < 5; ++j) {
        float4 w4 = *(const float4*)&s_xpc[g * 5 + j][kk];
        acc0[j] = fmaf(a0.x, w4.x, fmaf(a0.y, w4.y,
                  fmaf(a0.z, w4.z, fmaf(a0.w, w4.w, acc0[j]))));
        acc1[j] = fmaf(a1.x, w4.x, fmaf(a1.y, w4.y,
                  fmaf(a1.z, w4.z, fmaf(a1.w, w4.w, acc1[j]))));
      }
    }
  }
  __syncthreads();
#pragma unroll
  for (int j = 0; j < 5; ++j) {
    s_proj[lA][g * 5 + j]      = acc0[j];
    s_proj[lA + 32][g * 5 + j] = acc1[j];
  }
  __syncthreads();

  const int ll = t & 63;
  const int dgroup = t >> 6;
  float4 p0 = *(const float4*)&s_proj[ll][0];
  float4 p1 = *(const float4*)&s_proj[ll][4];
  for (int j = 0; j < 64; ++j) {
    int dout = dgroup * 64 + j;
    float4 w0 = *(const float4*)&s_dtw[dout * 8];
    float4 w1 = *(const float4*)&s_dtw[dout * 8 + 4];
    float v = s_dtb[dout]
            + p0.x * w0.x + p0.y * w0.y + p0.z * w0.z + p0.w * w0.w
            + p1.x * w1.x + p1.y * w1.y + p1.z * w1.z + p1.w * w1.w;
    dt_t[((size_t)(b * DINNER + dout)) * LSEQ + l0 + ll] = softplus_f(v);
  }
  if (t < 64) {
#pragma unroll
    for (int nn = 0; nn < 16; ++nn)
      Bt[((size_t)(b * NSTATE + nn)) * LSEQ + l0 + t] = s_proj[t][8 + nn];
  } else if (t < 128) {
    int lw = t - 64;
#pragma unroll
    for (int nn = 0; nn < 16; ++nn)
      Ct[((size_t)(b * NSTATE + nn)) * LSEQ + l0 + lw] = s_proj[lw][24 + nn];
  }
}

// ---------------------------------------------------------------------------
// Selective scan — EXACT R9/R17 plateau kernel (~160 µs/layer, absmax
// 1.746e-10). CLOSED after 7 failed depth attempts (R6/R7/R8/R9/R11-12/
// R16/R18): compiler waitcnt placement is group-granular depth-1 and
// invariant to source staging; 2-waves/CU TLP is the operative hiding.
// 8-step groups measured optimal (16-step = longer dependent tails, -18%).
// ---------------------------------------------------------------------------
__global__ __launch_bounds__(64) void scan_k(
    const float* __restrict__ dt_t, const float* __restrict__ u_t,
    const float* __restrict__ Bt,   const float* __restrict__ Ct,
    const float* __restrict__ A_log, const float* __restrict__ Dp,
    float* __restrict__ y_t)
{
  const int blk = blockIdx.x;
  const int b   = blk >> 6;
  const int d0  = (blk & 63) * 4;
  const int lane = threadIdx.x;
  const int g = lane >> 4;
  const int n = lane & 15;
  const int d = d0 + g;

  const float Aa = -expf(A_log[d * NSTATE + n]);
  const float Dv = Dp[d];
  const float4* dtp = (const float4*)(dt_t + ((size_t)(b * DINNER + d)) * LSEQ);
  const float4* up  = (const float4*)(u_t  + ((size_t)(b * DINNER + d)) * LSEQ);
  const float4* Bp  = (const float4*)(Bt + ((size_t)(b * NSTATE + n)) * LSEQ);
  const float4* Cp  = (const float4*)(Ct + ((size_t)(b * NSTATE + n)) * LSEQ);
  float4* yp = (float4*)(y_t + ((size_t)(b * DINNER + d)) * LSEQ);

  const int NG = LSEQ / 8;
  float4 Rd[4][2], Ru[4][2], Rb[4][2], Rc[4][2];
  float h = 0.f;

#define LOAD_GRP(s, grp) do {                                            \
    int _gg = (grp) < NG ? (grp) : NG - 1;                               \
    int _base = _gg * 2;                                                 \
    _Pragma("unroll")                                                    \
    for (int q = 0; q < 2; ++q) {                                        \
      Rd[s][q] = dtp[_base + q];  Ru[s][q] = up[_base + q];              \
      Rb[s][q] = Bp[_base + q];   Rc[s][q] = Cp[_base + q];              \
    }                                                                    \
  } while (0)

#define COMP_GRP(s, grp) do {                                            \
    float p[8], us8[8];                                                  \
    _Pragma("unroll")                                                    \
    for (int q = 0; q < 2; ++q) {                                        \
      float dts[4] = {Rd[s][q].x, Rd[s][q].y, Rd[s][q].z, Rd[s][q].w};   \
      float uq[4]  = {Ru[s][q].x, Ru[s][q].y, Ru[s][q].z, Ru[s][q].w};   \
      float bv[4]  = {Rb[s][q].x, Rb[s][q].y, Rb[s][q].z, Rb[s][q].w};   \
      float cv[4]  = {Rc[s][q].x, Rc[s][q].y, Rc[s][q].z, Rc[s][q].w};   \
      _Pragma("unroll")                                                  \
      for (int st = 0; st < 4; ++st) {                                   \
        int i = q * 4 + st;                                              \
        float a = __expf(dts[st] * Aa);                                  \
        h = fmaf(a, h, (dts[st] * uq[st]) * bv[st]);                     \
        p[i] = h * cv[st];                                               \
        us8[i] = uq[st];                                                 \
      }                                                                  \
    }                                                                    \
    _Pragma("unroll")                                                    \
    for (int i = 0; i < 8; ++i) p[i] += dpp_shift<0x118>(p[i]);          \
    _Pragma("unroll")                                                    \
    for (int i = 0; i < 8; ++i) p[i] += dpp_shift<0x114>(p[i]);          \
    _Pragma("unroll")                                                    \
    for (int i = 0; i < 8; ++i) p[i] += dpp_shift<0x112>(p[i]);          \
    _Pragma("unroll")                                                    \
    for (int i = 0; i < 8; ++i) p[i] += dpp_shift<0x111>(p[i]);          \
    if (n == 0) {                                                        \
      _Pragma("unroll")                                                  \
      for (int q = 0; q < 2; ++q)                                        \
        yp[(grp) * 2 + q] = make_float4(                                 \
            fmaf(us8[q*4+0], Dv, p[q*4+0]),                              \
            fmaf(us8[q*4+1], Dv, p[q*4+1]),                              \
            fmaf(us8[q*4+2], Dv, p[q*4+2]),                              \
            fmaf(us8[q*4+3], Dv, p[q*4+3]));                             \
    }                                                                    \
  } while (0)

  LOAD_GRP(0, 0);
  LOAD_GRP(1, 1);
  LOAD_GRP(2, 2);
  for (int it = 0; it < NG; it += 4) {
    LOAD_GRP(3, it + 3);
    COMP_GRP(0, it);
    LOAD_GRP(0, it + 4);
    COMP_GRP(1, it + 1);
    LOAD_GRP(1, it + 5);
    COMP_GRP(2, it + 2);
    LOAD_GRP(2, it + 6);
    COMP_GRP(3, it + 3);
  }
#undef LOAD_GRP
#undef COMP_GRP
}

// ---------------------------------------------------------------------------
extern "C" void kernel_launch(void* const* d_in, const int* in_sizes, int n_in,
                              void* d_out, int out_size, void* d_ws, size_t ws_size,
                              hipStream_t stream) {
  const float* x_in  = (const float*)d_in[0];
  const float* w_in  = (const float*)d_in[1];   // [4,512,128]
  const float* cw    = (const float*)d_in[2];   // [4,256,4]
  const float* cb    = (const float*)d_in[3];   // [4,256]
  const float* xpw   = (const float*)d_in[4];   // [4,40,256]
  const float* dtw   = (const float*)d_in[5];   // [4,256,8]
  const float* dtb   = (const float*)d_in[6];   // [4,256]
  const float* alog  = (const float*)d_in[7];   // [4,256,16]
  const float* Dp    = (const float*)d_in[8];   // [4,256]
  const float* ow    = (const float*)d_in[9];   // [4,128,256]
  float* out = (float*)d_out;

  const size_t M = MROWS;
  float* f0 = (float*)d_ws;            // x ping  [M,128]
  float* f1 = f0 + M * 128;            // x pong  [M,128]
  float* f2 = f1 + M * 128;            // xa_pre [M,256]
  float* f3 = f2 + M * 256;            // zs = silu(z) [M,256]
  float* f4 = f3 + M * 256;            // xa_t = u [B,256,L]
  float* f6 = f4 + M * 256;            // Bt [B,16,L]
  float* f7 = f6 + M * 16;             // Ct [B,16,L]
  float* f8 = f7 + M * 16;             // dt_t -> y_t (in-place) [B,256,L]

  const float* cur = x_in;
  for (int i = 0; i < NLAYER; ++i) {
    float* xout = (i == NLAYER - 1) ? out : ((i % 2 == 0) ? f0 : f1);
    const float* wi  = w_in + (size_t)i * 512 * 128;
    const float* cwi = cw   + (size_t)i * 256 * 4;
    const float* cbi = cb   + (size_t)i * 256;
    const float* xpi = xpw  + (size_t)i * 40 * 256;
    const float* dwi = dtw  + (size_t)i * 256 * 8;
    const float* dbi = dtb  + (size_t)i * 256;
    const float* ali = alog + (size_t)i * 256 * 16;
    const float* dpi = Dp   + (size_t)i * 256;
    const float* owi = ow   + (size_t)i * 128 * 256;

    // 1. in_proj (128x128 tile, A-prefetch): -> xa_pre(f2), silu(z)(f3)
    gemm_in<<<dim3(MROWS / 128, 4), 256, 0, stream>>>(cur, wi, f2, f3);
    // 2. fused conv + x_proj + dt_proj -> xa_t(f4), dt_t(f8), Bt(f6), Ct(f7)
    convproj_dt<<<dim3(LSEQ / 64, BATCH), 256, 0, stream>>>(
        f2, cwi, cbi, xpi, dwi, dbi, f4, f8, f6, f7);
    // 3. selective scan (exact R9/R17 8-step) -> y_t in-place over dt_t (f8)
    scan_k<<<dim3(BATCH * DINNER / 4), 64, 0, stream>>>(
        f8, f4, f6, f7, ali, dpi, f8);
    // 4. out_proj (64x128 tile) with fused y*silu(z) + transpose -> xout
    gemm_yz<<<dim3(MROWS / 64, 1), 256, 0, stream>>>(f8, f3, owi, xout);

    cur = xout;
  }
}